// Round 2
// baseline (330.255 us; speedup 1.0000x reference)
//
#include <hip/hip_runtime.h>
#include <math.h>

#define POUT 7
#define NCH 256

// ---------------- level geometry (elements) ----------------
// L0: HW=40000, L1: 10000, L2: 2500, L3: 625; B=2, C=256
#define HW0 40000
#define HW1 10000
#define HW2 2500
#define HW3 625
#define WS_OFF0 0
#define WS_OFF1 (2*NCH*HW0)                  // 20,480,000
#define WS_OFF2 (WS_OFF1 + 2*NCH*HW1)       // 25,600,000
#define WS_OFF3 (WS_OFF2 + 2*NCH*HW2)       // 26,880,000
#define WS_ELEMS (WS_OFF3 + 2*NCH*HW3)      // 27,200,000 elems = 108.8 MB

// ---------------- NCHW -> NHWC tiled transpose ----------------
// in: [B,256,HW] -> out: [B,HW,256]. Block (32,8), grid (ceil(HW/32), 8, B).
__global__ __launch_bounds__(256) void transpose_cl_kernel(
    const float* __restrict__ in, float* __restrict__ out, int HW)
{
    __shared__ float tile[32][33];
    const int p0 = blockIdx.x * 32;
    const int c0 = blockIdx.y * 32;
    const int b  = blockIdx.z;
    const int tx = threadIdx.x, ty = threadIdx.y;

    const float* src = in + ((size_t)b * NCH + c0) * (size_t)HW + p0;
    #pragma unroll
    for (int j = 0; j < 32; j += 8) {
        const int c = ty + j;
        if (p0 + tx < HW) tile[c][tx] = src[(size_t)c * HW + tx];
    }
    __syncthreads();
    float* dst = out + ((size_t)b * HW + p0) * NCH + c0;
    #pragma unroll
    for (int j = 0; j < 32; j += 8) {
        const int p = ty + j;
        if (p0 + p < HW) dst[(size_t)p * NCH + tx] = tile[tx][p];
    }
}

// ---------------- channels-last RoIAlign ----------------
// One block (256 threads) per box. Phase A: threads 0..195 compute the 196
// sample offsets/weights into LDS. Phase B: thread t = channel c; loads are
// 64 consecutive dwords per wave (fully coalesced).
__global__ __launch_bounds__(256) void roi_align_cl_kernel(
    const float* __restrict__ ws, const float* __restrict__ props,
    float* __restrict__ out, int boxes_per_img)
{
    __shared__ int   s_off[196][4];
    __shared__ float s_w[196][4];

    const int n = blockIdx.x;
    const int t = threadIdx.x;
    const int b = n / boxes_per_img;

    const float4 box = ((const float4*)props)[n];
    const float x0b = box.x, y0b = box.y, x1b = box.z, y1b = box.w;

    const float area = (x1b - x0b) * (y1b - y0b);
    const float side = sqrtf(area);
    float lvlf = floorf(4.0f + log2f(side / 224.0f + 1e-6f));
    lvlf = fminf(fmaxf(lvlf, 2.0f), 5.0f) - 2.0f;
    const int l = (int)lvlf;

    int sz; size_t lvl_off;
    if      (l == 0) { sz = 200; lvl_off = WS_OFF0; }
    else if (l == 1) { sz = 100; lvl_off = WS_OFF1; }
    else if (l == 2) { sz = 50;  lvl_off = WS_OFF2; }
    else             { sz = 25;  lvl_off = WS_OFF3; }
    const int HW = sz * sz;
    const float scale = 0.25f / (float)(1 << l);

    if (t < 196) {
        const int bin = t >> 2, q = t & 3;
        const int ph = bin / POUT, pw = bin % POUT;
        const int iy = q >> 1,    ix = q & 1;

        const float x0 = x0b * scale, y0 = y0b * scale;
        const float x1 = x1b * scale, y1 = y1b * scale;
        const float roi_w = fmaxf(x1 - x0, 1.0f);
        const float roi_h = fmaxf(y1 - y0, 1.0f);
        const float bin_w = roi_w / (float)POUT;
        const float bin_h = roi_h / (float)POUT;

        const float ysamp = y0 + ((float)ph + ((float)iy + 0.5f) * 0.5f) * bin_h;
        const float xsamp = x0 + ((float)pw + ((float)ix + 0.5f) * 0.5f) * bin_w;

        const bool  vy  = (ysamp >= -1.0f) && (ysamp <= (float)sz);
        const float cy  = fmaxf(ysamp, 0.0f);
        const int   yl0 = (int)floorf(cy);
        const bool  ey  = yl0 >= sz - 1;
        const int   yl  = ey ? sz - 1 : yl0;
        const int   yh  = ey ? sz - 1 : yl0 + 1;
        const float ly  = ey ? 0.0f : cy - (float)yl0;

        const bool  vx  = (xsamp >= -1.0f) && (xsamp <= (float)sz);
        const float cx  = fmaxf(xsamp, 0.0f);
        const int   xl0 = (int)floorf(cx);
        const bool  ex  = xl0 >= sz - 1;
        const int   xl  = ex ? sz - 1 : xl0;
        const int   xh  = ex ? sz - 1 : xl0 + 1;
        const float lx  = ex ? 0.0f : cx - (float)xl0;

        const float hy = 1.0f - ly, hx = 1.0f - lx;
        const float m  = (vy && vx) ? 0.25f : 0.0f;   // fold the /4 subsample mean
        s_w[t][0] = hy * hx * m;
        s_w[t][1] = hy * lx * m;
        s_w[t][2] = ly * hx * m;
        s_w[t][3] = ly * lx * m;
        s_off[t][0] = (yl * sz + xl) * NCH;
        s_off[t][1] = (yl * sz + xh) * NCH;
        s_off[t][2] = (yh * sz + xl) * NCH;
        s_off[t][3] = (yh * sz + xh) * NCH;
    }
    __syncthreads();

    const int c = t;
    const float* fb = ws + lvl_off + (size_t)b * (size_t)HW * NCH + c;
    float* op = out + ((size_t)n * NCH + c) * (POUT * POUT);

    for (int bin = 0; bin < 49; ++bin) {
        float a = 0.0f;
        #pragma unroll
        for (int q = 0; q < 4; ++q) {
            const int s = bin * 4 + q;
            const int4   o = *(const int4*)s_off[s];
            const float4 w = *(const float4*)s_w[s];
            a += w.x * fb[o.x] + w.y * fb[o.y] + w.z * fb[o.z] + w.w * fb[o.w];
        }
        op[bin] = a;
    }
}

// ---------------- fallback (round-1 NCHW kernel) ----------------
__global__ __launch_bounds__(256, 4) void roi_align_nchw_kernel(
    const float* __restrict__ f0, const float* __restrict__ f1,
    const float* __restrict__ f2, const float* __restrict__ f3,
    const float* __restrict__ props, float* __restrict__ out, int boxes_per_img)
{
    const int n = blockIdx.x;
    const int t = threadIdx.x;
    if (t >= 196) return;
    const int bin = t >> 2, q = t & 3;
    const int ph = bin / POUT, pw = bin % POUT;
    const int iy = q >> 1,    ix = q & 1;
    const int b = n / boxes_per_img;

    const float4 box = ((const float4*)props)[n];
    const float area = (box.z - box.x) * (box.w - box.y);
    float lvlf = floorf(4.0f + log2f(sqrtf(area) / 224.0f + 1e-6f));
    lvlf = fminf(fmaxf(lvlf, 2.0f), 5.0f) - 2.0f;
    const int l = (int)lvlf;

    const float* feat; int sz;
    if      (l == 0) { feat = f0; sz = 200; }
    else if (l == 1) { feat = f1; sz = 100; }
    else if (l == 2) { feat = f2; sz = 50;  }
    else             { feat = f3; sz = 25;  }
    const float scale = 0.25f / (float)(1 << l);

    const float x0 = box.x * scale, y0 = box.y * scale;
    const float x1 = box.z * scale, y1 = box.w * scale;
    const float bin_w = fmaxf(x1 - x0, 1.0f) / (float)POUT;
    const float bin_h = fmaxf(y1 - y0, 1.0f) / (float)POUT;
    const float ysamp = y0 + ((float)ph + ((float)iy + 0.5f) * 0.5f) * bin_h;
    const float xsamp = x0 + ((float)pw + ((float)ix + 0.5f) * 0.5f) * bin_w;

    const bool  vy  = (ysamp >= -1.0f) && (ysamp <= (float)sz);
    const float cy  = fmaxf(ysamp, 0.0f);
    const int   yl0 = (int)floorf(cy);
    const bool  ey  = yl0 >= sz - 1;
    const int   yl  = ey ? sz - 1 : yl0;
    const int   yh  = ey ? sz - 1 : yl0 + 1;
    const float ly  = ey ? 0.0f : cy - (float)yl0;
    const bool  vx  = (xsamp >= -1.0f) && (xsamp <= (float)sz);
    const float cx  = fmaxf(xsamp, 0.0f);
    const int   xl0 = (int)floorf(cx);
    const bool  ex  = xl0 >= sz - 1;
    const int   xl  = ex ? sz - 1 : xl0;
    const int   xh  = ex ? sz - 1 : xl0 + 1;
    const float lx  = ex ? 0.0f : cx - (float)xl0;

    const float hy = 1.0f - ly, hx = 1.0f - lx;
    const float m  = (vy && vx) ? 1.0f : 0.0f;
    const float w00 = hy * hx * m, w01 = hy * lx * m;
    const float w10 = ly * hx * m, w11 = ly * lx * m;

    const int HW = sz * sz;
    const float* base = feat + (size_t)b * NCH * HW;
    int o00 = yl * sz + xl, o01 = yl * sz + xh;
    int o10 = yh * sz + xl, o11 = yh * sz + xh;
    float* op = out + (size_t)n * NCH * (POUT * POUT) + bin;

    #pragma unroll 4
    for (int cch = 0; cch < NCH; ++cch) {
        float v = w00 * base[o00] + w01 * base[o01]
                + w10 * base[o10] + w11 * base[o11];
        v += __shfl_xor(v, 1);
        v += __shfl_xor(v, 2);
        if (q == 0) op[cch * (POUT * POUT)] = v * 0.25f;
        o00 += HW; o01 += HW; o10 += HW; o11 += HW;
    }
}

extern "C" void kernel_launch(void* const* d_in, const int* in_sizes, int n_in,
                              void* d_out, int out_size, void* d_ws, size_t ws_size,
                              hipStream_t stream) {
    const float* f0 = (const float*)d_in[0];
    const float* f1 = (const float*)d_in[1];
    const float* f2 = (const float*)d_in[2];
    const float* f3 = (const float*)d_in[3];
    const float* props = (const float*)d_in[4];
    float* out = (float*)d_out;

    const int N = in_sizes[4] / 4;                 // 1024 boxes
    const int B = in_sizes[0] / (NCH * HW0);       // 2 images
    const int boxes_per_img = N / B;               // 512

    if (ws_size >= (size_t)WS_ELEMS * sizeof(float)) {
        float* wsf = (float*)d_ws;
        dim3 blk(32, 8, 1);
        transpose_cl_kernel<<<dim3((HW0 + 31) / 32, 8, B), blk, 0, stream>>>(f0, wsf + WS_OFF0, HW0);
        transpose_cl_kernel<<<dim3((HW1 + 31) / 32, 8, B), blk, 0, stream>>>(f1, wsf + WS_OFF1, HW1);
        transpose_cl_kernel<<<dim3((HW2 + 31) / 32, 8, B), blk, 0, stream>>>(f2, wsf + WS_OFF2, HW2);
        transpose_cl_kernel<<<dim3((HW3 + 31) / 32, 8, B), blk, 0, stream>>>(f3, wsf + WS_OFF3, HW3);
        roi_align_cl_kernel<<<N, 256, 0, stream>>>(wsf, props, out, boxes_per_img);
    } else {
        roi_align_nchw_kernel<<<N, 256, 0, stream>>>(f0, f1, f2, f3, props, out, boxes_per_img);
    }
}